// Round 22
// baseline (234.602 us; speedup 1.0000x reference)
//
#include <hip/hip_runtime.h>
#include <stdint.h>

#define BATCH 32
#define M_TOT 3720          // 1000+1000+1000+576+144
#define NCAND 7440          // M_TOT * 2 classes
#define NPAD 8192
#define SCORE_THR 0.05f
#define IOU_THR 0.6f
#define RCLIP 4.135166556742356f
#define IMG 1536.0f

__device__ __forceinline__ float sigf(float x) {
    return __fdiv_rn(1.0f, __fadd_rn(1.0f, expf(-x)));
}

// LDS bank swizzle for u64 cu[]: XOR bits [6:4] into [2:0]. Bijective
// involution; permutes only within 8/16-aligned groups.
__device__ __forceinline__ unsigned swz(unsigned i) { return i ^ ((i >> 4) & 7u); }

struct P5 { const float* p[5]; };

// ---------- K1: keys + radix-select + 2048 register-bitonic rank + DECODE --
// After the sort each thread holds its <=2 ranked locations in registers and
// decodes them in-place (bit-identical k_decode math) -> boxes_g, scores_g.
// slots_g global round-trip eliminated.
template <int NPT>
__device__ __forceinline__ void select_level(
    const float* __restrict__ cls, const float* __restrict__ bbp,
    const float* __restrict__ ctr,
    int b, int hw, int w, int stride, int moff, int take,
    float* __restrict__ boxes_g, float* __restrict__ scores_g,
    unsigned long long* cu, unsigned* hist, unsigned* wtot,
    unsigned& sh_bin, unsigned& sh_krem, unsigned& sh_cnt)
{
    const int tid = threadIdx.x;
    float kv[NPT];
#pragma unroll
    for (int r = 0; r < NPT; ++r) {
        int i = tid + r * 1024;
        if (i < hw) {
            float s0 = sigf(cls[(size_t)(2*b)*hw + i]);
            float s1 = sigf(cls[(size_t)(2*b+1)*hw + i]);
            float sc = sigf(ctr[(size_t)b*hw + i]);
            kv[r] = __fmul_rn(fmaxf(s0, s1), sc);   // > 0 always
        } else {
            kv[r] = -1.0f;
        }
    }

    unsigned long long v[2];
    if (hw > 1000) {
        unsigned pref = 0, krem = 1000;
        for (int p = 0; p < 4; ++p) {
            const int shift = 24 - 8 * p;
            if (tid < 256) hist[tid] = 0;
            __syncthreads();
#pragma unroll
            for (int r = 0; r < NPT; ++r) {
                int i = tid + r * 1024;
                if (i < hw) {
                    unsigned u = __float_as_uint(kv[r]);
                    bool match = (p == 0) || ((u >> (shift + 8)) == pref);
                    if (match) atomicAdd(&hist[(u >> shift) & 255u], 1u);
                }
            }
            __syncthreads();
            unsigned h = 0, s = 0;
            if (tid < 256) {
                h = hist[tid];
                s = h;
#pragma unroll
                for (int d = 1; d < 64; d <<= 1) {
                    unsigned o = __shfl_down(s, d);
                    if ((tid & 63) + d < 64) s += o;
                }
                if ((tid & 63) == 0) wtot[tid >> 6] = s;
            }
            __syncthreads();
            if (tid < 256) {
                unsigned hi = 0;
                int wv = tid >> 6;
                for (int w2 = wv + 1; w2 < 4; ++w2) hi += wtot[w2];
                unsigned suf_incl = s + hi;
                unsigned suf_excl = suf_incl - h;
                if (suf_excl < krem && suf_incl >= krem) {
                    sh_bin = (unsigned)tid;
                    sh_krem = krem - suf_excl;
                    sh_cnt = 0;
                }
            }
            __syncthreads();
            pref = (pref << 8) | sh_bin;
            krem = sh_krem;
        }
        const unsigned T = pref;
        cu[tid] = ~0ULL; cu[tid + 1024] = ~0ULL;
        __syncthreads();
#pragma unroll
        for (int r = 0; r < NPT; ++r) {
            int i = tid + r * 1024;
            if (i < hw) {
                unsigned u = __float_as_uint(kv[r]);
                if (u >= T) {
                    unsigned pos = atomicAdd(&sh_cnt, 1u);
                    if (pos < 2048u)
                        cu[pos] = ~((((unsigned long long)u) << 20) | (unsigned)(0xFFFFF - i));
                }
            }
        }
        __syncthreads();
        v[0] = cu[tid * 2 + 0];
        v[1] = cu[tid * 2 + 1];
    } else {
#pragma unroll
        for (int r = 0; r < 2; ++r) {
            int i = tid * 2 + r;
            if (i < hw) {
                float s0 = sigf(cls[(size_t)(2*b)*hw + i]);
                float s1 = sigf(cls[(size_t)(2*b+1)*hw + i]);
                float sc = sigf(ctr[(size_t)b*hw + i]);
                unsigned u = __float_as_uint(__fmul_rn(fmaxf(s0, s1), sc));
                v[r] = ~((((unsigned long long)u) << 20) | (unsigned)(0xFFFFF - i));
            } else {
                v[r] = ~0ULL;
            }
        }
    }

    // bitonic sort 2048 ascending (green comparator; element i in thread i/2)
    for (unsigned kk = 2; kk <= 2048; kk <<= 1) {
        for (unsigned j = kk >> 1; j > 0; j >>= 1) {
            if (j >= 128) {
                __syncthreads();
                cu[swz(tid * 2 + 0)] = v[0];
                cu[swz(tid * 2 + 1)] = v[1];
                __syncthreads();
#pragma unroll
                for (int r = 0; r < 2; ++r) {
                    unsigned i = tid * 2 + r;
                    unsigned long long pv = cu[swz(i ^ j)];
                    bool up = ((i & kk) == 0);
                    bool lower = ((i & j) == 0);
                    bool keepmin = (lower == up);
                    v[r] = keepmin ? (v[r] < pv ? v[r] : pv)
                                   : (v[r] > pv ? v[r] : pv);
                }
            } else if (j >= 2) {
                unsigned m = j >> 1;
#pragma unroll
                for (int r = 0; r < 2; ++r) {
                    unsigned long long pv = __shfl_xor(v[r], (int)m, 64);
                    unsigned i = tid * 2 + r;
                    bool up = ((i & kk) == 0);
                    bool lower = ((i & j) == 0);
                    bool keepmin = (lower == up);
                    v[r] = keepmin ? (v[r] < pv ? v[r] : pv)
                                   : (v[r] > pv ? v[r] : pv);
                }
            } else {
                unsigned i = tid * 2;
                bool up = ((i & kk) == 0);
                if ((v[0] > v[1]) == up) {
                    unsigned long long t = v[0]; v[0] = v[1]; v[1] = t;
                }
            }
        }
    }

    // decode the <=2 ranked locations held in registers (k_decode math)
#pragma unroll
    for (int r = 0; r < 2; ++r) {
        int rank = tid * 2 + r;
        if (rank < take) {
            unsigned long long c = ~v[r];
            int loc = (int)(0xFFFFFu - (unsigned)(c & 0xFFFFFu));
            int m = moff + rank;

            float ctv = sigf(ctr[(size_t)b*hw + loc]);
            float sc0 = __fmul_rn(sigf(cls[(size_t)(2*b+0)*hw + loc]), ctv);
            float sc1 = __fmul_rn(sigf(cls[(size_t)(2*b+1)*hw + loc]), ctv);
            scores_g[(size_t)b * NCAND + 2*m + 0] = (sc0 > SCORE_THR) ? sc0 : -1.0f;
            scores_g[(size_t)b * NCAND + 2*m + 1] = (sc1 > SCORE_THR) ? sc1 : -1.0f;

            int yy = loc / w;
            int xx = loc - yy * w;
            float d0 = bbp[(size_t)(4*b+0)*hw + loc];
            float d1 = bbp[(size_t)(4*b+1)*hw + loc];
            float d2 = bbp[(size_t)(4*b+2)*hw + loc];
            float d3 = bbp[(size_t)(4*b+3)*hw + loc];
            float a   = (float)(8 * stride);
            float acx = (float)(xx * stride);
            float acy = (float)(yy * stride);
            float dwv = fminf(fmaxf(d2, -RCLIP), RCLIP);
            float dhv = fminf(fmaxf(d3, -RCLIP), RCLIP);
            float pcx = __fadd_rn(acx, __fmul_rn(d0, a));
            float pcy = __fadd_rn(acy, __fmul_rn(d1, a));
            float pw  = __fmul_rn(a, expf(dwv));
            float ph  = __fmul_rn(a, expf(dhv));
            float4 bx;
            bx.x = fminf(fmaxf(__fsub_rn(pcx, __fmul_rn(0.5f, pw)), 0.0f), IMG);
            bx.y = fminf(fmaxf(__fsub_rn(pcy, __fmul_rn(0.5f, ph)), 0.0f), IMG);
            bx.z = fminf(fmaxf(__fadd_rn(pcx, __fmul_rn(0.5f, pw)), 0.0f), IMG);
            bx.w = fminf(fmaxf(__fadd_rn(pcy, __fmul_rn(0.5f, ph)), 0.0f), IMG);
            ((float4*)boxes_g)[(size_t)b * M_TOT + m] = bx;
        }
    }
}

__global__ __launch_bounds__(1024) void k_sel_dec(P5 CLS, P5 BB, P5 CT,
                                                  float* __restrict__ boxes_g,
                                                  float* __restrict__ scores_g) {
    __shared__ unsigned long long cu[2048];
    __shared__ unsigned hist[256];
    __shared__ unsigned wtot[4];
    __shared__ unsigned sh_bin, sh_krem, sh_cnt;

    const int HWs[5]  = {36864, 9216, 2304, 576, 144};
    const int Ws[5]   = {192, 96, 48, 24, 12};
    const int STRs[5] = {8, 16, 32, 64, 128};
    const int MOFF[5] = {0, 1000, 2000, 3000, 3576};

    const int blk = blockIdx.x;        // 0..159
    const int b = blk / 5, l = blk % 5;
    const int hw = HWs[l];
    const int take = (hw < 1000) ? hw : 1000;

    if (l == 0)      select_level<36>(CLS.p[0], BB.p[0], CT.p[0], b, hw, Ws[0], STRs[0], MOFF[0], take, boxes_g, scores_g, cu, hist, wtot, sh_bin, sh_krem, sh_cnt);
    else if (l == 1) select_level<9> (CLS.p[1], BB.p[1], CT.p[1], b, hw, Ws[1], STRs[1], MOFF[1], take, boxes_g, scores_g, cu, hist, wtot, sh_bin, sh_krem, sh_cnt);
    else if (l == 2) select_level<3> (CLS.p[2], BB.p[2], CT.p[2], b, hw, Ws[2], STRs[2], MOFF[2], take, boxes_g, scores_g, cu, hist, wtot, sh_bin, sh_krem, sh_cnt);
    else if (l == 3) select_level<1> (CLS.p[3], BB.p[3], CT.p[3], b, hw, Ws[3], STRs[3], MOFF[3], take, boxes_g, scores_g, cu, hist, wtot, sh_bin, sh_krem, sh_cnt);
    else             select_level<1> (CLS.p[4], BB.p[4], CT.p[4], b, hw, Ws[4], STRs[4], MOFF[4], take, boxes_g, scores_g, cu, hist, wtot, sh_bin, sh_krem, sh_cnt);
}

// ---------- K3: register-bitonic sort (swizzled LDS) + class-split scan ----
// (byte-identical to green round 21)
__global__ __launch_bounds__(1024) void k_nms(const float* __restrict__ boxes_g,
                                              const float* __restrict__ scores_g,
                                              float* __restrict__ out) {
    __shared__ unsigned long long cu[NPAD];   // 64 KB
    const int b = blockIdx.x, tid = threadIdx.x;

    unsigned long long v[8];
    if (tid < 930) {
        const float4* s4 = (const float4*)(scores_g + (size_t)b * NCAND) + tid * 2;
        float4 a4 = s4[0], c4 = s4[1];
        float ss[8] = {a4.x, a4.y, a4.z, a4.w, c4.x, c4.y, c4.z, c4.w};
#pragma unroll
        for (int r = 0; r < 8; ++r) {
            int i = tid * 8 + r;
            v[r] = (ss[r] > 0.0f)
                ? ((((unsigned long long)(~__float_as_uint(ss[r]))) << 16) | (unsigned)i)
                : ~0ULL;
        }
    } else {
#pragma unroll
        for (int r = 0; r < 8; ++r) v[r] = ~0ULL;
    }

    for (unsigned kk = 2; kk <= NPAD; kk <<= 1) {
        for (unsigned j = kk >> 1; j > 0; j >>= 1) {
            if (j >= 512) {
                __syncthreads();
#pragma unroll
                for (int r = 0; r < 8; ++r) cu[swz(tid * 8 + r)] = v[r];
                __syncthreads();
#pragma unroll
                for (int r = 0; r < 8; ++r) {
                    unsigned i = tid * 8 + r;
                    unsigned long long pv = cu[swz(i ^ j)];
                    bool up = ((i & kk) == 0);
                    bool lower = ((i & j) == 0);
                    bool keepmin = (lower == up);
                    v[r] = keepmin ? (v[r] < pv ? v[r] : pv)
                                   : (v[r] > pv ? v[r] : pv);
                }
            } else if (j >= 8) {
                unsigned m = j >> 3;
#pragma unroll
                for (int r = 0; r < 8; ++r) {
                    unsigned long long pv = __shfl_xor(v[r], (int)m, 64);
                    unsigned i = tid * 8 + r;
                    bool up = ((i & kk) == 0);
                    bool lower = ((i & j) == 0);
                    bool keepmin = (lower == up);
                    v[r] = keepmin ? (v[r] < pv ? v[r] : pv)
                                   : (v[r] > pv ? v[r] : pv);
                }
            } else {
#pragma unroll
                for (int r = 0; r < 8; ++r) {
                    if ((r & j) == 0) {
                        unsigned i = tid * 8 + r;
                        bool up = ((i & kk) == 0);
                        unsigned long long a = v[r], b2 = v[r | j];
                        if ((a > b2) == up) { v[r] = b2; v[r | j] = a; }
                    }
                }
            }
        }
    }
    __syncthreads();
#pragma unroll
    for (int r = 0; r < 8; ++r) cu[swz(tid * 8 + r)] = v[r];
    __syncthreads();

    if (tid >= 64) return;   // wave 0 only; no more barriers

    const int lane = tid;
    const float4* bx4 = (const float4*)boxes_g + (size_t)b * M_TOT;
    float* keptL0 = (float*)(cu + NCAND);        // 500 floats
    float* keptL1 = keptL0 + 500;                // 500 floats

    int kc = 0, kc0 = 0, kc1 = 0;
    bool done = false;

    for (int base = 0; base < NCAND && kc < 100 && !done; base += 64) {
        unsigned long long e = (base + lane < NCAND) ? cu[swz(base + lane)] : ~0ULL;
        bool valid = (e != ~0ULL);
        unsigned myidx = (unsigned)(e & 0xFFFFull);
        float myscore = __uint_as_float(~(unsigned)(e >> 16));
        int myc = (int)(myidx & 1u);
        float bx1 = 0, by1 = 0, bx2 = 0, by2 = 0;
        if (valid) {
            float4 vv = bx4[myidx >> 1];
            bx1 = vv.x; by1 = vv.y; bx2 = vv.z; by2 = vv.w;
        }
        float offv = myc ? (IMG + 1.0f) : 0.0f;
        float ox1 = __fadd_rn(bx1, offv), oy1 = __fadd_rn(by1, offv);
        float ox2 = __fadd_rn(bx2, offv), oy2 = __fadd_rn(by2, offv);
        float ca = __fmul_rn(__fsub_rn(ox2, ox1), __fsub_rn(oy2, oy1));
        float uni_s = fmaxf(__fsub_rn(__fadd_rn(ca, ca), ca), 1e-6f);
        bool mySticky = !(__fdiv_rn(ca, uni_s) > IOU_THR);

        const bool hasInvalid = (__ballot(!valid) != 0ULL);

        bool ov = false;
        if (valid) {
            const int kcc = myc ? kc1 : kc0;
            const float* kl = myc ? keptL1 : keptL0;
            for (int k = 0; k < kcc && !ov; ++k) {
                float px1 = kl[k*5+0], py1 = kl[k*5+1];
                float px2 = kl[k*5+2], py2 = kl[k*5+3];
                float pa  = kl[k*5+4];
                float ix1 = fmaxf(px1, ox1), iy1 = fmaxf(py1, oy1);
                float ix2 = fminf(px2, ox2), iy2 = fminf(py2, oy2);
                float inter = __fmul_rn(fmaxf(__fsub_rn(ix2, ix1), 0.0f),
                                        fmaxf(__fsub_rn(iy2, iy1), 0.0f));
                float uni = fmaxf(__fsub_rn(__fadd_rn(pa, ca), inter), 1e-6f);
                ov = (__fdiv_rn(inter, uni) > IOU_THR);
            }
        }
        bool myAlive = valid && !ov;
        unsigned long long aliveMask = __ballot(myAlive);

        while (aliveMask != 0ULL && kc < 100) {
            int j = __ffsll(aliveMask) - 1;
            float pbx1 = __shfl(bx1, j), pby1 = __shfl(by1, j);
            float pbx2 = __shfl(bx2, j), pby2 = __shfl(by2, j);
            float pox1 = __shfl(ox1, j), poy1 = __shfl(oy1, j);
            float pox2 = __shfl(ox2, j), poy2 = __shfl(oy2, j);
            float pca  = __shfl(ca, j);
            float psc  = __shfl(myscore, j);
            int   pc   = __shfl(myc, j);
            int   pst  = __shfl((int)mySticky, j);

            if (pst) {
                for (int t2 = kc + lane; t2 < 100; t2 += 64) {
                    float* dr = out + ((size_t)b * 100 + t2) * 5;
                    dr[0] = pbx1; dr[1] = pby1; dr[2] = pbx2; dr[3] = pby2; dr[4] = psc;
                    out[(size_t)BATCH * 500 + b * 100 + t2] = (float)pc;
                }
                kc = 100;
                done = true;
                break;
            }
            if (lane == 0) {
                float* dr = out + ((size_t)b * 100 + kc) * 5;
                dr[0] = pbx1; dr[1] = pby1; dr[2] = pbx2; dr[3] = pby2; dr[4] = psc;
                out[(size_t)BATCH * 500 + b * 100 + kc] = (float)pc;
                float* kl = pc ? keptL1 : keptL0;
                int  kcx = pc ? kc1 : kc0;
                kl[kcx*5+0] = pox1; kl[kcx*5+1] = poy1;
                kl[kcx*5+2] = pox2; kl[kcx*5+3] = poy2;
                kl[kcx*5+4] = pca;
            }
            ++kc;
            if (pc) ++kc1; else ++kc0;
            if (myAlive && lane > j && myc == pc) {
                float ix1 = fmaxf(pox1, ox1), iy1 = fmaxf(poy1, oy1);
                float ix2 = fminf(pox2, ox2), iy2 = fminf(poy2, oy2);
                float inter = __fmul_rn(fmaxf(__fsub_rn(ix2, ix1), 0.0f),
                                        fmaxf(__fsub_rn(iy2, iy1), 0.0f));
                float uni = fmaxf(__fsub_rn(__fadd_rn(pca, ca), inter), 1e-6f);
                if (__fdiv_rn(inter, uni) > IOU_THR) myAlive = false;
            }
            if (lane == j) myAlive = false;
            aliveMask = __ballot(myAlive);
        }
        if (hasInvalid) break;
    }
    for (int t2 = kc + lane; t2 < 100; t2 += 64) {
        float* dr = out + ((size_t)b * 100 + t2) * 5;
        dr[0] = 0.0f; dr[1] = 0.0f; dr[2] = 0.0f; dr[3] = 0.0f; dr[4] = 0.0f;
        out[(size_t)BATCH * 500 + b * 100 + t2] = -1.0f;
    }
}

extern "C" void kernel_launch(void* const* d_in, const int* in_sizes, int n_in,
                              void* d_out, int out_size, void* d_ws, size_t ws_size,
                              hipStream_t stream) {
    static const int HW5[5] = {36864, 9216, 2304, 576, 144};
    int mc[5], mb[5], mt[5];
    bool found = false;
    for (int hyp = 0; hyp < 3 && !found; ++hyp) {
        bool ok = true;
        int tc[5], tb[5], tt[5];
        for (int l = 0; l < 5 && ok; ++l) {
            int ic, ib, it;
            if (hyp == 0)      { ic = 3*l;   ib = 3*l+1; it = 3*l+2; } // dict order
            else if (hyp == 1) { ic = l;     ib = 5+l;   it = 10+l;  } // arg order
            else               { ib = l;     ic = 5+l;   it = 10+l;  } // sorted keys
            if (in_sizes[ic] != 2*BATCH*HW5[l] ||
                in_sizes[ib] != 4*BATCH*HW5[l] ||
                in_sizes[it] != 1*BATCH*HW5[l]) ok = false;
            tc[l]=ic; tb[l]=ib; tt[l]=it;
        }
        if (ok) { for (int l=0;l<5;++l){mc[l]=tc[l];mb[l]=tb[l];mt[l]=tt[l];} found = true; }
    }
    if (!found) { for (int l=0;l<5;++l){mc[l]=3*l;mb[l]=3*l+1;mt[l]=3*l+2;} }

    P5 C, Bb, T;
    for (int l = 0; l < 5; ++l) {
        C.p[l]  = (const float*)d_in[mc[l]];
        Bb.p[l] = (const float*)d_in[mb[l]];
        T.p[l]  = (const float*)d_in[mt[l]];
    }

    uint8_t* w = (uint8_t*)d_ws;
    float* boxes_g  = (float*)w;                  // 1,904,640 B
    float* scores_g = (float*)(w + 2097152);      //   952,320 B

    k_sel_dec<<<dim3(160), dim3(1024), 0, stream>>>(C, Bb, T, boxes_g, scores_g);
    k_nms    <<<dim3(BATCH), dim3(1024), 0, stream>>>(boxes_g, scores_g, (float*)d_out);
}

// Round 23
// 223.552 us; speedup vs baseline: 1.0494x; 1.0494x over previous
//
#include <hip/hip_runtime.h>
#include <stdint.h>

#define BATCH 32
#define M_TOT 3720          // 1000+1000+1000+576+144
#define NCAND 7440          // M_TOT * 2 classes
#define NPAD 8192
#define SCORE_THR 0.05f
#define IOU_THR 0.6f
#define RCLIP 4.135166556742356f
#define IMG 1536.0f

__device__ __forceinline__ float sigf(float x) {
    return __fdiv_rn(1.0f, __fadd_rn(1.0f, expf(-x)));
}

// LDS bank swizzle for u64 cu[]: XOR bits [6:4] into [2:0]. Bijective
// involution; permutes only within 8/16-aligned groups.
__device__ __forceinline__ unsigned swz(unsigned i) { return i ^ ((i >> 4) & 7u); }

struct P5 { const float* p[5]; };

// ---------- K1: register keys + radix-select + 2048 register-bitonic rank --
// (byte-identical to green round 21)
template <int NPT>
__device__ __forceinline__ void select_level(
    const float* __restrict__ cls, const float* __restrict__ ctr,
    int b, int hw, int take, unsigned short* __restrict__ slots_out,
    unsigned long long* cu, unsigned* hist, unsigned* wtot,
    unsigned& sh_bin, unsigned& sh_krem, unsigned& sh_cnt)
{
    const int tid = threadIdx.x;
    float kv[NPT];
#pragma unroll
    for (int r = 0; r < NPT; ++r) {
        int i = tid + r * 1024;
        if (i < hw) {
            float s0 = sigf(cls[(size_t)(2*b)*hw + i]);
            float s1 = sigf(cls[(size_t)(2*b+1)*hw + i]);
            float sc = sigf(ctr[(size_t)b*hw + i]);
            kv[r] = __fmul_rn(fmaxf(s0, s1), sc);   // > 0 always
        } else {
            kv[r] = -1.0f;
        }
    }

    unsigned long long v[2];
    if (hw > 1000) {
        unsigned pref = 0, krem = 1000;
        for (int p = 0; p < 4; ++p) {
            const int shift = 24 - 8 * p;
            if (tid < 256) hist[tid] = 0;
            __syncthreads();
#pragma unroll
            for (int r = 0; r < NPT; ++r) {
                int i = tid + r * 1024;
                if (i < hw) {
                    unsigned u = __float_as_uint(kv[r]);
                    bool match = (p == 0) || ((u >> (shift + 8)) == pref);
                    if (match) atomicAdd(&hist[(u >> shift) & 255u], 1u);
                }
            }
            __syncthreads();
            unsigned h = 0, s = 0;
            if (tid < 256) {
                h = hist[tid];
                s = h;
#pragma unroll
                for (int d = 1; d < 64; d <<= 1) {
                    unsigned o = __shfl_down(s, d);
                    if ((tid & 63) + d < 64) s += o;
                }
                if ((tid & 63) == 0) wtot[tid >> 6] = s;
            }
            __syncthreads();
            if (tid < 256) {
                unsigned hi = 0;
                int wv = tid >> 6;
                for (int w2 = wv + 1; w2 < 4; ++w2) hi += wtot[w2];
                unsigned suf_incl = s + hi;
                unsigned suf_excl = suf_incl - h;
                if (suf_excl < krem && suf_incl >= krem) {
                    sh_bin = (unsigned)tid;
                    sh_krem = krem - suf_excl;
                    sh_cnt = 0;
                }
            }
            __syncthreads();
            pref = (pref << 8) | sh_bin;
            krem = sh_krem;
        }
        const unsigned T = pref;
        cu[tid] = ~0ULL; cu[tid + 1024] = ~0ULL;
        __syncthreads();
#pragma unroll
        for (int r = 0; r < NPT; ++r) {
            int i = tid + r * 1024;
            if (i < hw) {
                unsigned u = __float_as_uint(kv[r]);
                if (u >= T) {
                    unsigned pos = atomicAdd(&sh_cnt, 1u);
                    if (pos < 2048u)
                        cu[pos] = ~((((unsigned long long)u) << 20) | (unsigned)(0xFFFFF - i));
                }
            }
        }
        __syncthreads();
        v[0] = cu[tid * 2 + 0];
        v[1] = cu[tid * 2 + 1];
    } else {
#pragma unroll
        for (int r = 0; r < 2; ++r) {
            int i = tid * 2 + r;
            if (i < hw) {
                float s0 = sigf(cls[(size_t)(2*b)*hw + i]);
                float s1 = sigf(cls[(size_t)(2*b+1)*hw + i]);
                float sc = sigf(ctr[(size_t)b*hw + i]);
                unsigned u = __float_as_uint(__fmul_rn(fmaxf(s0, s1), sc));
                v[r] = ~((((unsigned long long)u) << 20) | (unsigned)(0xFFFFF - i));
            } else {
                v[r] = ~0ULL;
            }
        }
    }

    // bitonic sort 2048 ascending (green comparator; element i in thread i/2)
    for (unsigned kk = 2; kk <= 2048; kk <<= 1) {
        for (unsigned j = kk >> 1; j > 0; j >>= 1) {
            if (j >= 128) {
                __syncthreads();
                cu[swz(tid * 2 + 0)] = v[0];
                cu[swz(tid * 2 + 1)] = v[1];
                __syncthreads();
#pragma unroll
                for (int r = 0; r < 2; ++r) {
                    unsigned i = tid * 2 + r;
                    unsigned long long pv = cu[swz(i ^ j)];
                    bool up = ((i & kk) == 0);
                    bool lower = ((i & j) == 0);
                    bool keepmin = (lower == up);
                    v[r] = keepmin ? (v[r] < pv ? v[r] : pv)
                                   : (v[r] > pv ? v[r] : pv);
                }
            } else if (j >= 2) {
                unsigned m = j >> 1;
#pragma unroll
                for (int r = 0; r < 2; ++r) {
                    unsigned long long pv = __shfl_xor(v[r], (int)m, 64);
                    unsigned i = tid * 2 + r;
                    bool up = ((i & kk) == 0);
                    bool lower = ((i & j) == 0);
                    bool keepmin = (lower == up);
                    v[r] = keepmin ? (v[r] < pv ? v[r] : pv)
                                   : (v[r] > pv ? v[r] : pv);
                }
            } else {
                unsigned i = tid * 2;
                bool up = ((i & kk) == 0);
                if ((v[0] > v[1]) == up) {
                    unsigned long long t = v[0]; v[0] = v[1]; v[1] = t;
                }
            }
        }
    }
#pragma unroll
    for (int r = 0; r < 2; ++r) {
        int rank = tid * 2 + r;
        if (rank < take) {
            unsigned long long c = ~v[r];
            unsigned loc = 0xFFFFFu - (unsigned)(c & 0xFFFFFu);
            slots_out[rank] = (unsigned short)loc;
        }
    }
}

__global__ __launch_bounds__(1024) void k_select(P5 CLS, P5 CT,
                                                 unsigned short* __restrict__ slots_g) {
    __shared__ unsigned long long cu[2048];
    __shared__ unsigned hist[256];
    __shared__ unsigned wtot[4];
    __shared__ unsigned sh_bin, sh_krem, sh_cnt;

    const int HWs[5]  = {36864, 9216, 2304, 576, 144};
    const int MOFF[5] = {0, 1000, 2000, 3000, 3576};

    const int blk = blockIdx.x;        // 0..159
    const int b = blk / 5, l = blk % 5;
    const int hw = HWs[l];
    const int take = (hw < 1000) ? hw : 1000;
    unsigned short* slots_out = slots_g + (size_t)b * M_TOT + MOFF[l];

    if (l == 0)      select_level<36>(CLS.p[0], CT.p[0], b, hw, take, slots_out, cu, hist, wtot, sh_bin, sh_krem, sh_cnt);
    else if (l == 1) select_level<9> (CLS.p[1], CT.p[1], b, hw, take, slots_out, cu, hist, wtot, sh_bin, sh_krem, sh_cnt);
    else if (l == 2) select_level<3> (CLS.p[2], CT.p[2], b, hw, take, slots_out, cu, hist, wtot, sh_bin, sh_krem, sh_cnt);
    else if (l == 3) select_level<1> (CLS.p[3], CT.p[3], b, hw, take, slots_out, cu, hist, wtot, sh_bin, sh_krem, sh_cnt);
    else             select_level<1> (CLS.p[4], CT.p[4], b, hw, take, slots_out, cu, hist, wtot, sh_bin, sh_krem, sh_cnt);
}

// ---------- K2: decode boxes + candidate scores, wide (green round 21) -----
__global__ __launch_bounds__(256) void k_decode(P5 CLS, P5 BB, P5 CT,
                                                const unsigned short* __restrict__ slots_g,
                                                float* __restrict__ boxes_g,
                                                float* __restrict__ scores_g) {
    const int HWs[5]  = {36864, 9216, 2304, 576, 144};
    const int Ws[5]   = {192, 96, 48, 24, 12};
    const int STRs[5] = {8, 16, 32, 64, 128};
    int t = blockIdx.x * blockDim.x + threadIdx.x;
    if (t >= BATCH * M_TOT) return;
    int b = t / M_TOT;
    int m = t - b * M_TOT;
    int l;
    if (m < 1000)      l = 0;
    else if (m < 2000) l = 1;
    else if (m < 3000) l = 2;
    else if (m < 3576) l = 3;
    else               l = 4;
    const int hw = HWs[l], w = Ws[l], stride = STRs[l];
    int loc = slots_g[t];

    float ctv = sigf(CT.p[l][(size_t)b*hw + loc]);
    float sc0 = __fmul_rn(sigf(CLS.p[l][(size_t)(2*b+0)*hw + loc]), ctv);
    float sc1 = __fmul_rn(sigf(CLS.p[l][(size_t)(2*b+1)*hw + loc]), ctv);
    scores_g[(size_t)b * NCAND + 2*m + 0] = (sc0 > SCORE_THR) ? sc0 : -1.0f;
    scores_g[(size_t)b * NCAND + 2*m + 1] = (sc1 > SCORE_THR) ? sc1 : -1.0f;

    int yy = loc / w;
    int xx = loc - yy * w;
    const float* bb = BB.p[l];
    float d0 = bb[(size_t)(4*b+0)*hw + loc];
    float d1 = bb[(size_t)(4*b+1)*hw + loc];
    float d2 = bb[(size_t)(4*b+2)*hw + loc];
    float d3 = bb[(size_t)(4*b+3)*hw + loc];
    float a   = (float)(8 * stride);
    float acx = (float)(xx * stride);
    float acy = (float)(yy * stride);
    float dwv = fminf(fmaxf(d2, -RCLIP), RCLIP);
    float dhv = fminf(fmaxf(d3, -RCLIP), RCLIP);
    float pcx = __fadd_rn(acx, __fmul_rn(d0, a));
    float pcy = __fadd_rn(acy, __fmul_rn(d1, a));
    float pw  = __fmul_rn(a, expf(dwv));
    float ph  = __fmul_rn(a, expf(dhv));
    float* bx = boxes_g + (size_t)t * 4;
    bx[0] = fminf(fmaxf(__fsub_rn(pcx, __fmul_rn(0.5f, pw)), 0.0f), IMG);
    bx[1] = fminf(fmaxf(__fsub_rn(pcy, __fmul_rn(0.5f, ph)), 0.0f), IMG);
    bx[2] = fminf(fmaxf(__fadd_rn(pcx, __fmul_rn(0.5f, pw)), 0.0f), IMG);
    bx[3] = fminf(fmaxf(__fadd_rn(pcy, __fmul_rn(0.5f, ph)), 0.0f), IMG);
}

// ---------- K3: register-bitonic sort + class-split scan -------------------
// Scan change vs round 21: kept-check loop has NO early exit (ov |= ...)
// so iterations are independent -> compiler pipelines the LDS reads; kept
// records padded to 8 floats (float4 + scalar per iteration).
__global__ __launch_bounds__(1024) void k_nms(const float* __restrict__ boxes_g,
                                              const float* __restrict__ scores_g,
                                              float* __restrict__ out) {
    __shared__ unsigned long long cu[NPAD];   // 64 KB
    __shared__ __align__(16) float kept0[100 * 8];  // 3.2 KB, class-0 kept
    __shared__ __align__(16) float kept1[100 * 8];  // 3.2 KB, class-1 kept
    const int b = blockIdx.x, tid = threadIdx.x;

    unsigned long long v[8];
    if (tid < 930) {
        const float4* s4 = (const float4*)(scores_g + (size_t)b * NCAND) + tid * 2;
        float4 a4 = s4[0], c4 = s4[1];
        float ss[8] = {a4.x, a4.y, a4.z, a4.w, c4.x, c4.y, c4.z, c4.w};
#pragma unroll
        for (int r = 0; r < 8; ++r) {
            int i = tid * 8 + r;
            v[r] = (ss[r] > 0.0f)
                ? ((((unsigned long long)(~__float_as_uint(ss[r]))) << 16) | (unsigned)i)
                : ~0ULL;
        }
    } else {
#pragma unroll
        for (int r = 0; r < 8; ++r) v[r] = ~0ULL;
    }

    for (unsigned kk = 2; kk <= NPAD; kk <<= 1) {
        for (unsigned j = kk >> 1; j > 0; j >>= 1) {
            if (j >= 512) {
                __syncthreads();
#pragma unroll
                for (int r = 0; r < 8; ++r) cu[swz(tid * 8 + r)] = v[r];
                __syncthreads();
#pragma unroll
                for (int r = 0; r < 8; ++r) {
                    unsigned i = tid * 8 + r;
                    unsigned long long pv = cu[swz(i ^ j)];
                    bool up = ((i & kk) == 0);
                    bool lower = ((i & j) == 0);
                    bool keepmin = (lower == up);
                    v[r] = keepmin ? (v[r] < pv ? v[r] : pv)
                                   : (v[r] > pv ? v[r] : pv);
                }
            } else if (j >= 8) {
                unsigned m = j >> 3;
#pragma unroll
                for (int r = 0; r < 8; ++r) {
                    unsigned long long pv = __shfl_xor(v[r], (int)m, 64);
                    unsigned i = tid * 8 + r;
                    bool up = ((i & kk) == 0);
                    bool lower = ((i & j) == 0);
                    bool keepmin = (lower == up);
                    v[r] = keepmin ? (v[r] < pv ? v[r] : pv)
                                   : (v[r] > pv ? v[r] : pv);
                }
            } else {
#pragma unroll
                for (int r = 0; r < 8; ++r) {
                    if ((r & j) == 0) {
                        unsigned i = tid * 8 + r;
                        bool up = ((i & kk) == 0);
                        unsigned long long a = v[r], b2 = v[r | j];
                        if ((a > b2) == up) { v[r] = b2; v[r | j] = a; }
                    }
                }
            }
        }
    }
    __syncthreads();
#pragma unroll
    for (int r = 0; r < 8; ++r) cu[swz(tid * 8 + r)] = v[r];
    __syncthreads();

    if (tid >= 64) return;   // wave 0 only; no more barriers

    const int lane = tid;
    const float4* bx4 = (const float4*)boxes_g + (size_t)b * M_TOT;

    int kc = 0, kc0 = 0, kc1 = 0;
    bool done = false;

    for (int base = 0; base < NCAND && kc < 100 && !done; base += 64) {
        unsigned long long e = (base + lane < NCAND) ? cu[swz(base + lane)] : ~0ULL;
        bool valid = (e != ~0ULL);
        unsigned myidx = (unsigned)(e & 0xFFFFull);
        float myscore = __uint_as_float(~(unsigned)(e >> 16));
        int myc = (int)(myidx & 1u);
        float bx1 = 0, by1 = 0, bx2 = 0, by2 = 0;
        if (valid) {
            float4 vv = bx4[myidx >> 1];
            bx1 = vv.x; by1 = vv.y; bx2 = vv.z; by2 = vv.w;
        }
        float offv = myc ? (IMG + 1.0f) : 0.0f;
        float ox1 = __fadd_rn(bx1, offv), oy1 = __fadd_rn(by1, offv);
        float ox2 = __fadd_rn(bx2, offv), oy2 = __fadd_rn(by2, offv);
        float ca = __fmul_rn(__fsub_rn(ox2, ox1), __fsub_rn(oy2, oy1));
        float uni_s = fmaxf(__fsub_rn(__fadd_rn(ca, ca), ca), 1e-6f);
        bool mySticky = !(__fdiv_rn(ca, uni_s) > IOU_THR);

        const bool hasInvalid = (__ballot(!valid) != 0ULL);

        // same-class kept check, NO early exit (independent iterations ->
        // LDS reads pipeline). ov is the same boolean OR either way.
        bool ov = false;
        if (valid) {
            const int kcc = myc ? kc1 : kc0;
            const float* kl = myc ? kept1 : kept0;
#pragma unroll 2
            for (int k = 0; k < kcc; ++k) {
                float4 p4 = *(const float4*)(kl + k * 8);
                float pa  = kl[k * 8 + 4];
                float ix1 = fmaxf(p4.x, ox1), iy1 = fmaxf(p4.y, oy1);
                float ix2 = fminf(p4.z, ox2), iy2 = fminf(p4.w, oy2);
                float inter = __fmul_rn(fmaxf(__fsub_rn(ix2, ix1), 0.0f),
                                        fmaxf(__fsub_rn(iy2, iy1), 0.0f));
                float uni = fmaxf(__fsub_rn(__fadd_rn(pa, ca), inter), 1e-6f);
                ov = ov | (__fdiv_rn(inter, uni) > IOU_THR);
            }
        }
        bool myAlive = valid && !ov;
        unsigned long long aliveMask = __ballot(myAlive);

        while (aliveMask != 0ULL && kc < 100) {
            int j = __ffsll(aliveMask) - 1;
            float pbx1 = __shfl(bx1, j), pby1 = __shfl(by1, j);
            float pbx2 = __shfl(bx2, j), pby2 = __shfl(by2, j);
            float pox1 = __shfl(ox1, j), poy1 = __shfl(oy1, j);
            float pox2 = __shfl(ox2, j), poy2 = __shfl(oy2, j);
            float pca  = __shfl(ca, j);
            float psc  = __shfl(myscore, j);
            int   pc   = __shfl(myc, j);
            int   pst  = __shfl((int)mySticky, j);

            if (pst) {
                for (int t2 = kc + lane; t2 < 100; t2 += 64) {
                    float* dr = out + ((size_t)b * 100 + t2) * 5;
                    dr[0] = pbx1; dr[1] = pby1; dr[2] = pbx2; dr[3] = pby2; dr[4] = psc;
                    out[(size_t)BATCH * 500 + b * 100 + t2] = (float)pc;
                }
                kc = 100;
                done = true;
                break;
            }
            if (lane == 0) {
                float* dr = out + ((size_t)b * 100 + kc) * 5;
                dr[0] = pbx1; dr[1] = pby1; dr[2] = pbx2; dr[3] = pby2; dr[4] = psc;
                out[(size_t)BATCH * 500 + b * 100 + kc] = (float)pc;
                float* kl = pc ? kept1 : kept0;
                int  kcx = pc ? kc1 : kc0;
                kl[kcx*8+0] = pox1; kl[kcx*8+1] = poy1;
                kl[kcx*8+2] = pox2; kl[kcx*8+3] = poy2;
                kl[kcx*8+4] = pca;
            }
            ++kc;
            if (pc) ++kc1; else ++kc0;
            if (myAlive && lane > j && myc == pc) {
                float ix1 = fmaxf(pox1, ox1), iy1 = fmaxf(poy1, oy1);
                float ix2 = fminf(pox2, ox2), iy2 = fminf(poy2, oy2);
                float inter = __fmul_rn(fmaxf(__fsub_rn(ix2, ix1), 0.0f),
                                        fmaxf(__fsub_rn(iy2, iy1), 0.0f));
                float uni = fmaxf(__fsub_rn(__fadd_rn(pca, ca), inter), 1e-6f);
                if (__fdiv_rn(inter, uni) > IOU_THR) myAlive = false;
            }
            if (lane == j) myAlive = false;
            aliveMask = __ballot(myAlive);
        }
        if (hasInvalid) break;
    }
    for (int t2 = kc + lane; t2 < 100; t2 += 64) {
        float* dr = out + ((size_t)b * 100 + t2) * 5;
        dr[0] = 0.0f; dr[1] = 0.0f; dr[2] = 0.0f; dr[3] = 0.0f; dr[4] = 0.0f;
        out[(size_t)BATCH * 500 + b * 100 + t2] = -1.0f;
    }
}

extern "C" void kernel_launch(void* const* d_in, const int* in_sizes, int n_in,
                              void* d_out, int out_size, void* d_ws, size_t ws_size,
                              hipStream_t stream) {
    static const int HW5[5] = {36864, 9216, 2304, 576, 144};
    int mc[5], mb[5], mt[5];
    bool found = false;
    for (int hyp = 0; hyp < 3 && !found; ++hyp) {
        bool ok = true;
        int tc[5], tb[5], tt[5];
        for (int l = 0; l < 5 && ok; ++l) {
            int ic, ib, it;
            if (hyp == 0)      { ic = 3*l;   ib = 3*l+1; it = 3*l+2; } // dict order
            else if (hyp == 1) { ic = l;     ib = 5+l;   it = 10+l;  } // arg order
            else               { ib = l;     ic = 5+l;   it = 10+l;  } // sorted keys
            if (in_sizes[ic] != 2*BATCH*HW5[l] ||
                in_sizes[ib] != 4*BATCH*HW5[l] ||
                in_sizes[it] != 1*BATCH*HW5[l]) ok = false;
            tc[l]=ic; tb[l]=ib; tt[l]=it;
        }
        if (ok) { for (int l=0;l<5;++l){mc[l]=tc[l];mb[l]=tb[l];mt[l]=tt[l];} found = true; }
    }
    if (!found) { for (int l=0;l<5;++l){mc[l]=3*l;mb[l]=3*l+1;mt[l]=3*l+2;} }

    P5 C, Bb, T;
    for (int l = 0; l < 5; ++l) {
        C.p[l]  = (const float*)d_in[mc[l]];
        Bb.p[l] = (const float*)d_in[mb[l]];
        T.p[l]  = (const float*)d_in[mt[l]];
    }

    uint8_t* w = (uint8_t*)d_ws;
    float*          boxes_g  = (float*)w;                        // 1,904,640 B
    float*          scores_g = (float*)(w + 2097152);            //   952,320 B
    unsigned short* slots_g  = (unsigned short*)(w + 6291456);   //   238,080 B

    k_select<<<dim3(160), dim3(1024), 0, stream>>>(C, T, slots_g);
    k_decode<<<dim3((BATCH*M_TOT + 255)/256), dim3(256), 0, stream>>>(
        C, Bb, T, slots_g, boxes_g, scores_g);
    k_nms   <<<dim3(BATCH), dim3(1024), 0, stream>>>(boxes_g, scores_g, (float*)d_out);
}

// Round 24
// 223.392 us; speedup vs baseline: 1.0502x; 1.0007x over previous
//
#include <hip/hip_runtime.h>
#include <stdint.h>

#define BATCH 32
#define M_TOT 3720          // 1000+1000+1000+576+144
#define NCAND 7440          // M_TOT * 2 classes
#define NPAD 8192
#define SCORE_THR 0.05f
#define IOU_THR 0.6f
#define RCLIP 4.135166556742356f
#define IMG 1536.0f

__device__ __forceinline__ float sigf(float x) {
    return __fdiv_rn(1.0f, __fadd_rn(1.0f, expf(-x)));
}

// LDS bank swizzle for u64 cu[]: XOR bits [6:4] into [2:0]. Bijective
// involution; permutes only within 8/16-aligned groups.
__device__ __forceinline__ unsigned swz(unsigned i) { return i ^ ((i >> 4) & 7u); }

struct P5 { const float* p[5]; };

// ---------- K1: register keys + radix-select + 2048 register-bitonic rank --
// (byte-identical to green round 23)
template <int NPT>
__device__ __forceinline__ void select_level(
    const float* __restrict__ cls, const float* __restrict__ ctr,
    int b, int hw, int take, unsigned short* __restrict__ slots_out,
    unsigned long long* cu, unsigned* hist, unsigned* wtot,
    unsigned& sh_bin, unsigned& sh_krem, unsigned& sh_cnt)
{
    const int tid = threadIdx.x;
    float kv[NPT];
#pragma unroll
    for (int r = 0; r < NPT; ++r) {
        int i = tid + r * 1024;
        if (i < hw) {
            float s0 = sigf(cls[(size_t)(2*b)*hw + i]);
            float s1 = sigf(cls[(size_t)(2*b+1)*hw + i]);
            float sc = sigf(ctr[(size_t)b*hw + i]);
            kv[r] = __fmul_rn(fmaxf(s0, s1), sc);   // > 0 always
        } else {
            kv[r] = -1.0f;
        }
    }

    unsigned long long v[2];
    if (hw > 1000) {
        unsigned pref = 0, krem = 1000;
        for (int p = 0; p < 4; ++p) {
            const int shift = 24 - 8 * p;
            if (tid < 256) hist[tid] = 0;
            __syncthreads();
#pragma unroll
            for (int r = 0; r < NPT; ++r) {
                int i = tid + r * 1024;
                if (i < hw) {
                    unsigned u = __float_as_uint(kv[r]);
                    bool match = (p == 0) || ((u >> (shift + 8)) == pref);
                    if (match) atomicAdd(&hist[(u >> shift) & 255u], 1u);
                }
            }
            __syncthreads();
            unsigned h = 0, s = 0;
            if (tid < 256) {
                h = hist[tid];
                s = h;
#pragma unroll
                for (int d = 1; d < 64; d <<= 1) {
                    unsigned o = __shfl_down(s, d);
                    if ((tid & 63) + d < 64) s += o;
                }
                if ((tid & 63) == 0) wtot[tid >> 6] = s;
            }
            __syncthreads();
            if (tid < 256) {
                unsigned hi = 0;
                int wv = tid >> 6;
                for (int w2 = wv + 1; w2 < 4; ++w2) hi += wtot[w2];
                unsigned suf_incl = s + hi;
                unsigned suf_excl = suf_incl - h;
                if (suf_excl < krem && suf_incl >= krem) {
                    sh_bin = (unsigned)tid;
                    sh_krem = krem - suf_excl;
                    sh_cnt = 0;
                }
            }
            __syncthreads();
            pref = (pref << 8) | sh_bin;
            krem = sh_krem;
        }
        const unsigned T = pref;
        cu[tid] = ~0ULL; cu[tid + 1024] = ~0ULL;
        __syncthreads();
#pragma unroll
        for (int r = 0; r < NPT; ++r) {
            int i = tid + r * 1024;
            if (i < hw) {
                unsigned u = __float_as_uint(kv[r]);
                if (u >= T) {
                    unsigned pos = atomicAdd(&sh_cnt, 1u);
                    if (pos < 2048u)
                        cu[pos] = ~((((unsigned long long)u) << 20) | (unsigned)(0xFFFFF - i));
                }
            }
        }
        __syncthreads();
        v[0] = cu[tid * 2 + 0];
        v[1] = cu[tid * 2 + 1];
    } else {
#pragma unroll
        for (int r = 0; r < 2; ++r) {
            int i = tid * 2 + r;
            if (i < hw) {
                float s0 = sigf(cls[(size_t)(2*b)*hw + i]);
                float s1 = sigf(cls[(size_t)(2*b+1)*hw + i]);
                float sc = sigf(ctr[(size_t)b*hw + i]);
                unsigned u = __float_as_uint(__fmul_rn(fmaxf(s0, s1), sc));
                v[r] = ~((((unsigned long long)u) << 20) | (unsigned)(0xFFFFF - i));
            } else {
                v[r] = ~0ULL;
            }
        }
    }

    // bitonic sort 2048 ascending (green comparator; element i in thread i/2)
    for (unsigned kk = 2; kk <= 2048; kk <<= 1) {
        for (unsigned j = kk >> 1; j > 0; j >>= 1) {
            if (j >= 128) {
                __syncthreads();
                cu[swz(tid * 2 + 0)] = v[0];
                cu[swz(tid * 2 + 1)] = v[1];
                __syncthreads();
#pragma unroll
                for (int r = 0; r < 2; ++r) {
                    unsigned i = tid * 2 + r;
                    unsigned long long pv = cu[swz(i ^ j)];
                    bool up = ((i & kk) == 0);
                    bool lower = ((i & j) == 0);
                    bool keepmin = (lower == up);
                    v[r] = keepmin ? (v[r] < pv ? v[r] : pv)
                                   : (v[r] > pv ? v[r] : pv);
                }
            } else if (j >= 2) {
                unsigned m = j >> 1;
#pragma unroll
                for (int r = 0; r < 2; ++r) {
                    unsigned long long pv = __shfl_xor(v[r], (int)m, 64);
                    unsigned i = tid * 2 + r;
                    bool up = ((i & kk) == 0);
                    bool lower = ((i & j) == 0);
                    bool keepmin = (lower == up);
                    v[r] = keepmin ? (v[r] < pv ? v[r] : pv)
                                   : (v[r] > pv ? v[r] : pv);
                }
            } else {
                unsigned i = tid * 2;
                bool up = ((i & kk) == 0);
                if ((v[0] > v[1]) == up) {
                    unsigned long long t = v[0]; v[0] = v[1]; v[1] = t;
                }
            }
        }
    }
#pragma unroll
    for (int r = 0; r < 2; ++r) {
        int rank = tid * 2 + r;
        if (rank < take) {
            unsigned long long c = ~v[r];
            unsigned loc = 0xFFFFFu - (unsigned)(c & 0xFFFFFu);
            slots_out[rank] = (unsigned short)loc;
        }
    }
}

__global__ __launch_bounds__(1024) void k_select(P5 CLS, P5 CT,
                                                 unsigned short* __restrict__ slots_g) {
    __shared__ unsigned long long cu[2048];
    __shared__ unsigned hist[256];
    __shared__ unsigned wtot[4];
    __shared__ unsigned sh_bin, sh_krem, sh_cnt;

    const int HWs[5]  = {36864, 9216, 2304, 576, 144};
    const int MOFF[5] = {0, 1000, 2000, 3000, 3576};

    const int blk = blockIdx.x;        // 0..159
    const int b = blk / 5, l = blk % 5;
    const int hw = HWs[l];
    const int take = (hw < 1000) ? hw : 1000;
    unsigned short* slots_out = slots_g + (size_t)b * M_TOT + MOFF[l];

    if (l == 0)      select_level<36>(CLS.p[0], CT.p[0], b, hw, take, slots_out, cu, hist, wtot, sh_bin, sh_krem, sh_cnt);
    else if (l == 1) select_level<9> (CLS.p[1], CT.p[1], b, hw, take, slots_out, cu, hist, wtot, sh_bin, sh_krem, sh_cnt);
    else if (l == 2) select_level<3> (CLS.p[2], CT.p[2], b, hw, take, slots_out, cu, hist, wtot, sh_bin, sh_krem, sh_cnt);
    else if (l == 3) select_level<1> (CLS.p[3], CT.p[3], b, hw, take, slots_out, cu, hist, wtot, sh_bin, sh_krem, sh_cnt);
    else             select_level<1> (CLS.p[4], CT.p[4], b, hw, take, slots_out, cu, hist, wtot, sh_bin, sh_krem, sh_cnt);
}

// ---------- K2: decode boxes + candidate scores, wide (green round 21) -----
__global__ __launch_bounds__(256) void k_decode(P5 CLS, P5 BB, P5 CT,
                                                const unsigned short* __restrict__ slots_g,
                                                float* __restrict__ boxes_g,
                                                float* __restrict__ scores_g) {
    const int HWs[5]  = {36864, 9216, 2304, 576, 144};
    const int Ws[5]   = {192, 96, 48, 24, 12};
    const int STRs[5] = {8, 16, 32, 64, 128};
    int t = blockIdx.x * blockDim.x + threadIdx.x;
    if (t >= BATCH * M_TOT) return;
    int b = t / M_TOT;
    int m = t - b * M_TOT;
    int l;
    if (m < 1000)      l = 0;
    else if (m < 2000) l = 1;
    else if (m < 3000) l = 2;
    else if (m < 3576) l = 3;
    else               l = 4;
    const int hw = HWs[l], w = Ws[l], stride = STRs[l];
    int loc = slots_g[t];

    float ctv = sigf(CT.p[l][(size_t)b*hw + loc]);
    float sc0 = __fmul_rn(sigf(CLS.p[l][(size_t)(2*b+0)*hw + loc]), ctv);
    float sc1 = __fmul_rn(sigf(CLS.p[l][(size_t)(2*b+1)*hw + loc]), ctv);
    scores_g[(size_t)b * NCAND + 2*m + 0] = (sc0 > SCORE_THR) ? sc0 : -1.0f;
    scores_g[(size_t)b * NCAND + 2*m + 1] = (sc1 > SCORE_THR) ? sc1 : -1.0f;

    int yy = loc / w;
    int xx = loc - yy * w;
    const float* bb = BB.p[l];
    float d0 = bb[(size_t)(4*b+0)*hw + loc];
    float d1 = bb[(size_t)(4*b+1)*hw + loc];
    float d2 = bb[(size_t)(4*b+2)*hw + loc];
    float d3 = bb[(size_t)(4*b+3)*hw + loc];
    float a   = (float)(8 * stride);
    float acx = (float)(xx * stride);
    float acy = (float)(yy * stride);
    float dwv = fminf(fmaxf(d2, -RCLIP), RCLIP);
    float dhv = fminf(fmaxf(d3, -RCLIP), RCLIP);
    float pcx = __fadd_rn(acx, __fmul_rn(d0, a));
    float pcy = __fadd_rn(acy, __fmul_rn(d1, a));
    float pw  = __fmul_rn(a, expf(dwv));
    float ph  = __fmul_rn(a, expf(dhv));
    float* bx = boxes_g + (size_t)t * 4;
    bx[0] = fminf(fmaxf(__fsub_rn(pcx, __fmul_rn(0.5f, pw)), 0.0f), IMG);
    bx[1] = fminf(fmaxf(__fsub_rn(pcy, __fmul_rn(0.5f, ph)), 0.0f), IMG);
    bx[2] = fminf(fmaxf(__fadd_rn(pcx, __fmul_rn(0.5f, pw)), 0.0f), IMG);
    bx[3] = fminf(fmaxf(__fadd_rn(pcy, __fmul_rn(0.5f, ph)), 0.0f), IMG);
}

// ---------- K3: register-bitonic sort + LDS-staged boxes + scan ------------
// Change vs round 23: ALL boxes staged into LDS (59.5 KB) cooperatively by
// 16 waves before the sort; scan's per-candidate gather becomes a pipelined
// LDS read instead of an exposed global miss. Total LDS 130 KB < 160 KB.
__global__ __launch_bounds__(1024) void k_nms(const float* __restrict__ boxes_g,
                                              const float* __restrict__ scores_g,
                                              float* __restrict__ out) {
    __shared__ unsigned long long cu[NPAD];          // 64 KB
    __shared__ __align__(16) float s_box[M_TOT * 4]; // 59.5 KB
    __shared__ __align__(16) float kept0[100 * 8];   // 3.2 KB
    __shared__ __align__(16) float kept1[100 * 8];   // 3.2 KB
    const int b = blockIdx.x, tid = threadIdx.x;

    // cooperative box staging (coalesced, 4 float4/thread)
    {
        const float4* src = (const float4*)boxes_g + (size_t)b * M_TOT;
        for (int m = tid; m < M_TOT; m += 1024)
            *(float4*)(s_box + m * 4) = src[m];
    }

    unsigned long long v[8];
    if (tid < 930) {
        const float4* s4 = (const float4*)(scores_g + (size_t)b * NCAND) + tid * 2;
        float4 a4 = s4[0], c4 = s4[1];
        float ss[8] = {a4.x, a4.y, a4.z, a4.w, c4.x, c4.y, c4.z, c4.w};
#pragma unroll
        for (int r = 0; r < 8; ++r) {
            int i = tid * 8 + r;
            v[r] = (ss[r] > 0.0f)
                ? ((((unsigned long long)(~__float_as_uint(ss[r]))) << 16) | (unsigned)i)
                : ~0ULL;
        }
    } else {
#pragma unroll
        for (int r = 0; r < 8; ++r) v[r] = ~0ULL;
    }

    for (unsigned kk = 2; kk <= NPAD; kk <<= 1) {
        for (unsigned j = kk >> 1; j > 0; j >>= 1) {
            if (j >= 512) {
                __syncthreads();
#pragma unroll
                for (int r = 0; r < 8; ++r) cu[swz(tid * 8 + r)] = v[r];
                __syncthreads();
#pragma unroll
                for (int r = 0; r < 8; ++r) {
                    unsigned i = tid * 8 + r;
                    unsigned long long pv = cu[swz(i ^ j)];
                    bool up = ((i & kk) == 0);
                    bool lower = ((i & j) == 0);
                    bool keepmin = (lower == up);
                    v[r] = keepmin ? (v[r] < pv ? v[r] : pv)
                                   : (v[r] > pv ? v[r] : pv);
                }
            } else if (j >= 8) {
                unsigned m = j >> 3;
#pragma unroll
                for (int r = 0; r < 8; ++r) {
                    unsigned long long pv = __shfl_xor(v[r], (int)m, 64);
                    unsigned i = tid * 8 + r;
                    bool up = ((i & kk) == 0);
                    bool lower = ((i & j) == 0);
                    bool keepmin = (lower == up);
                    v[r] = keepmin ? (v[r] < pv ? v[r] : pv)
                                   : (v[r] > pv ? v[r] : pv);
                }
            } else {
#pragma unroll
                for (int r = 0; r < 8; ++r) {
                    if ((r & j) == 0) {
                        unsigned i = tid * 8 + r;
                        bool up = ((i & kk) == 0);
                        unsigned long long a = v[r], b2 = v[r | j];
                        if ((a > b2) == up) { v[r] = b2; v[r | j] = a; }
                    }
                }
            }
        }
    }
    __syncthreads();
#pragma unroll
    for (int r = 0; r < 8; ++r) cu[swz(tid * 8 + r)] = v[r];
    __syncthreads();

    if (tid >= 64) return;   // wave 0 only; no more barriers

    const int lane = tid;

    int kc = 0, kc0 = 0, kc1 = 0;
    bool done = false;

    for (int base = 0; base < NCAND && kc < 100 && !done; base += 64) {
        unsigned long long e = (base + lane < NCAND) ? cu[swz(base + lane)] : ~0ULL;
        bool valid = (e != ~0ULL);
        unsigned myidx = (unsigned)(e & 0xFFFFull);
        float myscore = __uint_as_float(~(unsigned)(e >> 16));
        int myc = (int)(myidx & 1u);
        float bx1 = 0, by1 = 0, bx2 = 0, by2 = 0;
        if (valid) {
            float4 vv = *(const float4*)(s_box + (myidx >> 1) * 4);
            bx1 = vv.x; by1 = vv.y; bx2 = vv.z; by2 = vv.w;
        }
        float offv = myc ? (IMG + 1.0f) : 0.0f;
        float ox1 = __fadd_rn(bx1, offv), oy1 = __fadd_rn(by1, offv);
        float ox2 = __fadd_rn(bx2, offv), oy2 = __fadd_rn(by2, offv);
        float ca = __fmul_rn(__fsub_rn(ox2, ox1), __fsub_rn(oy2, oy1));
        float uni_s = fmaxf(__fsub_rn(__fadd_rn(ca, ca), ca), 1e-6f);
        bool mySticky = !(__fdiv_rn(ca, uni_s) > IOU_THR);

        const bool hasInvalid = (__ballot(!valid) != 0ULL);

        // same-class kept check, no early exit (iterations independent)
        bool ov = false;
        if (valid) {
            const int kcc = myc ? kc1 : kc0;
            const float* kl = myc ? kept1 : kept0;
#pragma unroll 2
            for (int k = 0; k < kcc; ++k) {
                float4 p4 = *(const float4*)(kl + k * 8);
                float pa  = kl[k * 8 + 4];
                float ix1 = fmaxf(p4.x, ox1), iy1 = fmaxf(p4.y, oy1);
                float ix2 = fminf(p4.z, ox2), iy2 = fminf(p4.w, oy2);
                float inter = __fmul_rn(fmaxf(__fsub_rn(ix2, ix1), 0.0f),
                                        fmaxf(__fsub_rn(iy2, iy1), 0.0f));
                float uni = fmaxf(__fsub_rn(__fadd_rn(pa, ca), inter), 1e-6f);
                ov = ov | (__fdiv_rn(inter, uni) > IOU_THR);
            }
        }
        bool myAlive = valid && !ov;
        unsigned long long aliveMask = __ballot(myAlive);

        while (aliveMask != 0ULL && kc < 100) {
            int j = __ffsll(aliveMask) - 1;
            float pbx1 = __shfl(bx1, j), pby1 = __shfl(by1, j);
            float pbx2 = __shfl(bx2, j), pby2 = __shfl(by2, j);
            float pox1 = __shfl(ox1, j), poy1 = __shfl(oy1, j);
            float pox2 = __shfl(ox2, j), poy2 = __shfl(oy2, j);
            float pca  = __shfl(ca, j);
            float psc  = __shfl(myscore, j);
            int   pc   = __shfl(myc, j);
            int   pst  = __shfl((int)mySticky, j);

            if (pst) {
                for (int t2 = kc + lane; t2 < 100; t2 += 64) {
                    float* dr = out + ((size_t)b * 100 + t2) * 5;
                    dr[0] = pbx1; dr[1] = pby1; dr[2] = pbx2; dr[3] = pby2; dr[4] = psc;
                    out[(size_t)BATCH * 500 + b * 100 + t2] = (float)pc;
                }
                kc = 100;
                done = true;
                break;
            }
            if (lane == 0) {
                float* dr = out + ((size_t)b * 100 + kc) * 5;
                dr[0] = pbx1; dr[1] = pby1; dr[2] = pbx2; dr[3] = pby2; dr[4] = psc;
                out[(size_t)BATCH * 500 + b * 100 + kc] = (float)pc;
                float* kl = pc ? kept1 : kept0;
                int  kcx = pc ? kc1 : kc0;
                kl[kcx*8+0] = pox1; kl[kcx*8+1] = poy1;
                kl[kcx*8+2] = pox2; kl[kcx*8+3] = poy2;
                kl[kcx*8+4] = pca;
            }
            ++kc;
            if (pc) ++kc1; else ++kc0;
            if (myAlive && lane > j && myc == pc) {
                float ix1 = fmaxf(pox1, ox1), iy1 = fmaxf(poy1, oy1);
                float ix2 = fminf(pox2, ox2), iy2 = fminf(poy2, oy2);
                float inter = __fmul_rn(fmaxf(__fsub_rn(ix2, ix1), 0.0f),
                                        fmaxf(__fsub_rn(iy2, iy1), 0.0f));
                float uni = fmaxf(__fsub_rn(__fadd_rn(pca, ca), inter), 1e-6f);
                if (__fdiv_rn(inter, uni) > IOU_THR) myAlive = false;
            }
            if (lane == j) myAlive = false;
            aliveMask = __ballot(myAlive);
        }
        if (hasInvalid) break;
    }
    for (int t2 = kc + lane; t2 < 100; t2 += 64) {
        float* dr = out + ((size_t)b * 100 + t2) * 5;
        dr[0] = 0.0f; dr[1] = 0.0f; dr[2] = 0.0f; dr[3] = 0.0f; dr[4] = 0.0f;
        out[(size_t)BATCH * 500 + b * 100 + t2] = -1.0f;
    }
}

extern "C" void kernel_launch(void* const* d_in, const int* in_sizes, int n_in,
                              void* d_out, int out_size, void* d_ws, size_t ws_size,
                              hipStream_t stream) {
    static const int HW5[5] = {36864, 9216, 2304, 576, 144};
    int mc[5], mb[5], mt[5];
    bool found = false;
    for (int hyp = 0; hyp < 3 && !found; ++hyp) {
        bool ok = true;
        int tc[5], tb[5], tt[5];
        for (int l = 0; l < 5 && ok; ++l) {
            int ic, ib, it;
            if (hyp == 0)      { ic = 3*l;   ib = 3*l+1; it = 3*l+2; } // dict order
            else if (hyp == 1) { ic = l;     ib = 5+l;   it = 10+l;  } // arg order
            else               { ib = l;     ic = 5+l;   it = 10+l;  } // sorted keys
            if (in_sizes[ic] != 2*BATCH*HW5[l] ||
                in_sizes[ib] != 4*BATCH*HW5[l] ||
                in_sizes[it] != 1*BATCH*HW5[l]) ok = false;
            tc[l]=ic; tb[l]=ib; tt[l]=it;
        }
        if (ok) { for (int l=0;l<5;++l){mc[l]=tc[l];mb[l]=tb[l];mt[l]=tt[l];} found = true; }
    }
    if (!found) { for (int l=0;l<5;++l){mc[l]=3*l;mb[l]=3*l+1;mt[l]=3*l+2;} }

    P5 C, Bb, T;
    for (int l = 0; l < 5; ++l) {
        C.p[l]  = (const float*)d_in[mc[l]];
        Bb.p[l] = (const float*)d_in[mb[l]];
        T.p[l]  = (const float*)d_in[mt[l]];
    }

    uint8_t* w = (uint8_t*)d_ws;
    float*          boxes_g  = (float*)w;                        // 1,904,640 B
    float*          scores_g = (float*)(w + 2097152);            //   952,320 B
    unsigned short* slots_g  = (unsigned short*)(w + 6291456);   //   238,080 B

    k_select<<<dim3(160), dim3(1024), 0, stream>>>(C, T, slots_g);
    k_decode<<<dim3((BATCH*M_TOT + 255)/256), dim3(256), 0, stream>>>(
        C, Bb, T, slots_g, boxes_g, scores_g);
    k_nms   <<<dim3(BATCH), dim3(1024), 0, stream>>>(boxes_g, scores_g, (float*)d_out);
}